// Round 1
// baseline (3301.475 us; speedup 1.0000x reference)
//
#include <hip/hip_runtime.h>
#include <cmath>

#define Nn   100000
#define Ee   1600000
#define FIN  256
#define Hh   128
#define EDIMM 16
#define NL   3
#define NOUT 64
#define EPB  64

// ---------------- in_proj: h = x @ in_w + in_b  [N,256]@[256,128] ----------------
__global__ __launch_bounds__(128) void in_proj_kernel(const float* __restrict__ x,
    const float* __restrict__ w, const float* __restrict__ b, float* __restrict__ h) {
  __shared__ float xs[8][FIN];
  int r0 = blockIdx.x * 8;
  for (int i = threadIdx.x; i < 8 * FIN; i += 128) {
    int r = i >> 8, c = i & (FIN - 1);
    int rr = r0 + r;
    xs[r][c] = (rr < Nn) ? x[rr * FIN + c] : 0.f;
  }
  __syncthreads();
  int t = threadIdx.x;  // output column 0..127
  float acc[8] = {0,0,0,0,0,0,0,0};
  for (int kk = 0; kk < FIN; kk++) {
    float wv = w[kk * Hh + t];
#pragma unroll
    for (int r = 0; r < 8; r++) acc[r] += xs[r][kk] * wv;
  }
  float bias = b[t];
#pragma unroll
  for (int r = 0; r < 8; r++) {
    int rr = r0 + r;
    if (rr < Nn) h[rr * Hh + t] = acc[r] + bias;
  }
}

// ---- fused k,q,v,skip: 4x [N,128]@[128,128], reads h once ----
__global__ __launch_bounds__(128) void kqvs_kernel(const float* __restrict__ h,
    const float* __restrict__ Wk, const float* __restrict__ bk,
    const float* __restrict__ Wq, const float* __restrict__ bq,
    const float* __restrict__ Wv, const float* __restrict__ bv,
    const float* __restrict__ Ws, const float* __restrict__ bs,
    float* __restrict__ kout, float* __restrict__ qout,
    float* __restrict__ vout, float* __restrict__ hnew) {
  __shared__ float hs[8][Hh];
  int r0 = blockIdx.x * 8;
  for (int i = threadIdx.x; i < 8 * Hh; i += 128) {
    int r = i >> 7, c = i & 127;
    int rr = r0 + r;
    hs[r][c] = (rr < Nn) ? h[rr * Hh + c] : 0.f;
  }
  __syncthreads();
  int t = threadIdx.x;
  float ak[8] = {}, aq[8] = {}, av[8] = {}, as_[8] = {};
  for (int kk = 0; kk < Hh; kk++) {
    float wk = Wk[kk * Hh + t];
    float wq = Wq[kk * Hh + t];
    float wv = Wv[kk * Hh + t];
    float ws = Ws[kk * Hh + t];
#pragma unroll
    for (int r = 0; r < 8; r++) {
      float hv = hs[r][kk];
      ak[r] += hv * wk;
      aq[r] += hv * wq;
      av[r] += hv * wv;
      as_[r] += hv * ws;
    }
  }
  float bkv = bk[t], bqv = bq[t], bvv = bv[t], bsv = bs[t];
#pragma unroll
  for (int r = 0; r < 8; r++) {
    int rr = r0 + r;
    if (rr < Nn) {
      kout[rr * Hh + t] = ak[r] + bkv;
      qout[rr * Hh + t] = aq[r] + bqv;
      vout[rr * Hh + t] = av[r] + bvv;
      hnew[rr * Hh + t] = as_[r] + bsv;
    }
  }
}

// ---- fused edge kernel: e-embed + gate + msg + scatter-add ----
// gate = sigmoid(k[dst] + e + q[src]); msg = gate * v[src]; hnew[dst] += msg
__global__ __launch_bounds__(256) void edge_kernel(
    const float* __restrict__ kbuf, const float* __restrict__ qbuf,
    const float* __restrict__ vbuf, const int* __restrict__ ei,
    const float* __restrict__ ea, const float* __restrict__ We_l,
    const float* __restrict__ be_l, float* __restrict__ hnew) {
  __shared__ float sWe[EDIMM * Hh];
  __shared__ float sbe[Hh];
  for (int i = threadIdx.x; i < EDIMM * Hh; i += 256) sWe[i] = We_l[i];
  if (threadIdx.x < Hh) sbe[threadIdx.x] = be_l[threadIdx.x];
  __syncthreads();
  int lane = threadIdx.x & 127;   // channel
  int grp  = threadIdx.x >> 7;    // 0..1
  int e0 = blockIdx.x * EPB;
  for (int i = grp; i < EPB; i += 2) {
    int e = e0 + i;
    if (e >= Ee) break;
    int src = ei[e];        // row 0: source j
    int dst = ei[Ee + e];   // row 1: target i
    const float* ear = ea + e * EDIMM;
    float acc = sbe[lane];
#pragma unroll
    for (int d = 0; d < EDIMM; d++) acc += ear[d] * sWe[d * Hh + lane];
    float g = kbuf[dst * Hh + lane] + acc + qbuf[src * Hh + lane];
    g = 1.f / (1.f + __expf(-g));
    float m = g * vbuf[src * Hh + lane];
    atomicAdd(&hnew[dst * Hh + lane], m);
  }
}

// ---- LayerNorm (eps=1e-5) + exact GELU, in place, one wave per row ----
__global__ __launch_bounds__(256) void ln_gelu_kernel(float* __restrict__ h,
    const float* __restrict__ g, const float* __restrict__ b) {
  int wave = threadIdx.x >> 6;
  int lane = threadIdx.x & 63;
  int row = blockIdx.x * 4 + wave;
  if (row >= Nn) return;
  float* hr = h + (size_t)row * Hh;
  float v0 = hr[lane], v1 = hr[lane + 64];
  float s = v0 + v1;
#pragma unroll
  for (int off = 32; off; off >>= 1) s += __shfl_xor(s, off);
  float mu = s * (1.f / 128.f);
  float d0 = v0 - mu, d1 = v1 - mu;
  float vv = d0 * d0 + d1 * d1;
#pragma unroll
  for (int off = 32; off; off >>= 1) vv += __shfl_xor(vv, off);
  float rstd = rsqrtf(vv * (1.f / 128.f) + 1e-5f);
  float y0 = d0 * rstd * g[lane] + b[lane];
  float y1 = d1 * rstd * g[lane + 64] + b[lane + 64];
  y0 = 0.5f * y0 * (1.f + erff(y0 * 0.70710678118654752f));
  y1 = 0.5f * y1 * (1.f + erff(y1 * 0.70710678118654752f));
  hr[lane] = y0;
  hr[lane + 64] = y1;
}

// ---- out_proj: out = h @ out_w  [N,128]@[128,64] ----
__global__ __launch_bounds__(64) void out_proj_kernel(const float* __restrict__ h,
    const float* __restrict__ w, float* __restrict__ out) {
  __shared__ float hs[16][Hh];
  int r0 = blockIdx.x * 16;
  for (int i = threadIdx.x; i < 16 * Hh; i += 64) {
    int r = i >> 7, c = i & 127;
    int rr = r0 + r;
    hs[r][c] = (rr < Nn) ? h[rr * Hh + c] : 0.f;
  }
  __syncthreads();
  int t = threadIdx.x;  // col 0..63
  float acc[16] = {};
  for (int kk = 0; kk < Hh; kk++) {
    float wv = w[kk * NOUT + t];
#pragma unroll
    for (int r = 0; r < 16; r++) acc[r] += hs[r][kk] * wv;
  }
#pragma unroll
  for (int r = 0; r < 16; r++) {
    int rr = r0 + r;
    if (rr < Nn) out[rr * NOUT + t] = acc[r];
  }
}

extern "C" void kernel_launch(void* const* d_in, const int* in_sizes, int n_in,
                              void* d_out, int out_size, void* d_ws, size_t ws_size,
                              hipStream_t stream) {
  const float* x    = (const float*)d_in[0];
  const int*   ei   = (const int*)d_in[1];
  const float* ea   = (const float*)d_in[2];
  const float* in_w = (const float*)d_in[3];
  const float* in_b = (const float*)d_in[4];
  const float* Wk   = (const float*)d_in[5];
  const float* bk   = (const float*)d_in[6];
  const float* Wq   = (const float*)d_in[7];
  const float* bq   = (const float*)d_in[8];
  const float* Wv   = (const float*)d_in[9];
  const float* bv   = (const float*)d_in[10];
  const float* We   = (const float*)d_in[11];
  const float* be   = (const float*)d_in[12];
  const float* Ws   = (const float*)d_in[13];
  const float* bs   = (const float*)d_in[14];
  const float* ln_g = (const float*)d_in[15];
  const float* ln_b = (const float*)d_in[16];
  const float* out_w = (const float*)d_in[17];
  float* out = (float*)d_out;

  size_t NH = (size_t)Nn * Hh;
  float* hA = (float*)d_ws;
  float* hB = hA + NH;
  float* kb = hB + NH;
  float* qb = kb + NH;
  float* vb = qb + NH;

  in_proj_kernel<<<(Nn + 7) / 8, 128, 0, stream>>>(x, in_w, in_b, hA);

  float* h  = hA;
  float* hn = hB;
  for (int l = 0; l < NL; l++) {
    kqvs_kernel<<<(Nn + 7) / 8, 128, 0, stream>>>(h,
        Wk + l * Hh * Hh, bk + l * Hh,
        Wq + l * Hh * Hh, bq + l * Hh,
        Wv + l * Hh * Hh, bv + l * Hh,
        Ws + l * Hh * Hh, bs + l * Hh,
        kb, qb, vb, hn);
    edge_kernel<<<(Ee + EPB - 1) / EPB, 256, 0, stream>>>(kb, qb, vb, ei, ea,
        We + l * EDIMM * Hh, be + l * Hh, hn);
    ln_gelu_kernel<<<(Nn + 3) / 4, 256, 0, stream>>>(hn, ln_g + l * Hh, ln_b + l * Hh);
    float* tmp = h; h = hn; hn = tmp;
  }

  out_proj_kernel<<<(Nn + 15) / 16, 64, 0, stream>>>(h, out_w, out);
}

// Round 2
// 2455.550 us; speedup vs baseline: 1.3445x; 1.3445x over previous
//
#include <hip/hip_runtime.h>
#include <hip/hip_fp16.h>
#include <cmath>

#define Nn   100000
#define Ee   1600000
#define FIN  256
#define Hh   128
#define EDIMM 16
#define NL   3
#define NOUT 64

// ---------------- in_proj: h = x @ in_w + in_b  [N,256]@[256,128] ----------------
__global__ __launch_bounds__(128) void in_proj_kernel(const float* __restrict__ x,
    const float* __restrict__ w, const float* __restrict__ b, float* __restrict__ h) {
  __shared__ float xs[8][FIN];
  int r0 = blockIdx.x * 8;
  for (int i = threadIdx.x; i < 8 * FIN; i += 128) {
    int r = i >> 8, c = i & (FIN - 1);
    int rr = r0 + r;
    xs[r][c] = (rr < Nn) ? x[rr * FIN + c] : 0.f;
  }
  __syncthreads();
  int t = threadIdx.x;
  float acc[8] = {};
  for (int kk = 0; kk < FIN; kk++) {
    float wv = w[kk * Hh + t];
#pragma unroll
    for (int r = 0; r < 8; r++) acc[r] += xs[r][kk] * wv;
  }
  float bias = b[t];
#pragma unroll
  for (int r = 0; r < 8; r++) {
    int rr = r0 + r;
    if (rr < Nn) h[rr * Hh + t] = acc[r] + bias;
  }
}

// ---- fused k,q,v,skip: 4x [N,128]@[128,128]; k/q/v stored fp16, skip fp32 ----
__global__ __launch_bounds__(128) void kqvs_kernel(const float* __restrict__ h,
    const float* __restrict__ Wk, const float* __restrict__ bk,
    const float* __restrict__ Wq, const float* __restrict__ bq,
    const float* __restrict__ Wv, const float* __restrict__ bv,
    const float* __restrict__ Ws, const float* __restrict__ bs,
    __half* __restrict__ kout, __half* __restrict__ qout,
    __half* __restrict__ vout, float* __restrict__ hnew) {
  __shared__ float hs[8][Hh];
  int r0 = blockIdx.x * 8;
  for (int i = threadIdx.x; i < 8 * Hh; i += 128) {
    int r = i >> 7, c = i & 127;
    int rr = r0 + r;
    hs[r][c] = (rr < Nn) ? h[rr * Hh + c] : 0.f;
  }
  __syncthreads();
  int t = threadIdx.x;
  float ak[8] = {}, aq[8] = {}, av[8] = {}, as_[8] = {};
  for (int kk = 0; kk < Hh; kk++) {
    float wk = Wk[kk * Hh + t];
    float wq = Wq[kk * Hh + t];
    float wv = Wv[kk * Hh + t];
    float ws = Ws[kk * Hh + t];
#pragma unroll
    for (int r = 0; r < 8; r++) {
      float hv = hs[r][kk];
      ak[r] += hv * wk;
      aq[r] += hv * wq;
      av[r] += hv * wv;
      as_[r] += hv * ws;
    }
  }
  float bkv = bk[t], bqv = bq[t], bvv = bv[t], bsv = bs[t];
#pragma unroll
  for (int r = 0; r < 8; r++) {
    int rr = r0 + r;
    if (rr < Nn) {
      kout[rr * Hh + t] = __float2half(ak[r] + bkv);
      qout[rr * Hh + t] = __float2half(aq[r] + bqv);
      vout[rr * Hh + t] = __float2half(av[r] + bvv);
      hnew[rr * Hh + t] = as_[r] + bsv;
    }
  }
}

// ---------------- CSR build ----------------
__global__ __launch_bounds__(256) void zero_kernel(int* __restrict__ p, int n) {
  int i = blockIdx.x * 256 + threadIdx.x;
  if (i < n) p[i] = 0;
}

__global__ __launch_bounds__(256) void hist_kernel(const int* __restrict__ ei_dst,
                                                   int* __restrict__ counts) {
  int e = blockIdx.x * 256 + threadIdx.x;
  if (e < Ee) atomicAdd(&counts[ei_dst[e]], 1);
}

// each block scans 1024 counts -> per-block exclusive scan + block total
__global__ __launch_bounds__(256) void scan_block_kernel(const int* __restrict__ counts,
    int* __restrict__ rowptr, int* __restrict__ bsums) {
  __shared__ int tsums[256];
  int b = blockIdx.x, t = threadIdx.x;
  int base = b * 1024 + t * 4;
  int v[4]; int s = 0;
#pragma unroll
  for (int j = 0; j < 4; j++) {
    int idx = base + j;
    v[j] = (idx < Nn) ? counts[idx] : 0;
    s += v[j];
  }
  tsums[t] = s;
  __syncthreads();
  for (int off = 1; off < 256; off <<= 1) {
    int y = (t >= off) ? tsums[t - off] : 0;
    __syncthreads();
    tsums[t] += y;
    __syncthreads();
  }
  int excl = tsums[t] - s;   // exclusive prefix for this thread's 4 elems
#pragma unroll
  for (int j = 0; j < 4; j++) {
    int idx = base + j;
    if (idx < Nn) rowptr[idx] = excl;
    excl += v[j];
  }
  if (t == 255) bsums[b] = tsums[255];
}

__global__ __launch_bounds__(128) void scan_sums_kernel(int* __restrict__ bsums, int nb) {
  __shared__ int sh[128];
  int t = threadIdx.x;
  int v = (t < nb) ? bsums[t] : 0;
  sh[t] = v;
  __syncthreads();
  for (int off = 1; off < 128; off <<= 1) {
    int y = (t >= off) ? sh[t - off] : 0;
    __syncthreads();
    sh[t] += y;
    __syncthreads();
  }
  if (t < nb) bsums[t] = sh[t] - v;  // exclusive
}

__global__ __launch_bounds__(256) void finalize_rowptr_kernel(int* __restrict__ rowptr,
    const int* __restrict__ bsums, int* __restrict__ cursor) {
  int i = blockIdx.x * 256 + threadIdx.x;
  if (i < Nn) {
    int r = rowptr[i] + bsums[i >> 10];
    rowptr[i] = r;
    cursor[i] = r;
  }
  if (i == Nn) rowptr[Nn] = Ee;
}

__global__ __launch_bounds__(256) void fill_kernel(const int* __restrict__ ei_dst,
    int* __restrict__ cursor, int* __restrict__ eid) {
  int e = blockIdx.x * 256 + threadIdx.x;
  if (e < Ee) {
    int d = ei_dst[e];
    int slot = atomicAdd(&cursor[d], 1);
    eid[slot] = e;
  }
}

// ---- CSR edge kernel: one wave per dst row; fused skip-add + LN + GELU ----
__global__ __launch_bounds__(256) void edge_csr_kernel(
    const __half* __restrict__ kb, const __half* __restrict__ qb,
    const __half* __restrict__ vb, const int* __restrict__ ei_src,
    const float* __restrict__ ea, const int* __restrict__ rowptr,
    const int* __restrict__ eid,
    const float* __restrict__ We_l, const float* __restrict__ be_l,
    const float* __restrict__ ln_g_l, const float* __restrict__ ln_b_l,
    float* __restrict__ hbuf) {
  int wave = threadIdx.x >> 6;
  int lane = threadIdx.x & 63;
  int row = blockIdx.x * 4 + wave;   // grid sized exactly: 25000*4 = 100000
  int c0 = lane * 2;                 // this lane owns channels c0, c0+1

  // We columns for my two channels -> registers (16 x 2)
  float w0[EDIMM], w1[EDIMM];
#pragma unroll
  for (int d = 0; d < EDIMM; d++) {
    float2 wv = *(const float2*)(We_l + d * Hh + c0);
    w0[d] = wv.x; w1[d] = wv.y;
  }
  float2 bev = *(const float2*)(be_l + c0);

  __half2 kh = *(const __half2*)(kb + (size_t)row * Hh + c0);
  float k0 = __half2float(kh.x), k1 = __half2float(kh.y);

  float agg0 = 0.f, agg1 = 0.f;
  int beg = rowptr[row], end = rowptr[row + 1];
  for (int e = beg; e < end; e++) {
    int eidx = eid[e];
    int src = ei_src[eidx];
    const float4* ea4 = (const float4*)(ea + (size_t)eidx * EDIMM);
    float4 a0 = ea4[0], a1 = ea4[1], a2 = ea4[2], a3 = ea4[3];
    float emb0 = bev.x, emb1 = bev.y;
    emb0 += a0.x*w0[0] + a0.y*w0[1] + a0.z*w0[2] + a0.w*w0[3];
    emb1 += a0.x*w1[0] + a0.y*w1[1] + a0.z*w1[2] + a0.w*w1[3];
    emb0 += a1.x*w0[4] + a1.y*w0[5] + a1.z*w0[6] + a1.w*w0[7];
    emb1 += a1.x*w1[4] + a1.y*w1[5] + a1.z*w1[6] + a1.w*w1[7];
    emb0 += a2.x*w0[8] + a2.y*w0[9] + a2.z*w0[10] + a2.w*w0[11];
    emb1 += a2.x*w1[8] + a2.y*w1[9] + a2.z*w1[10] + a2.w*w1[11];
    emb0 += a3.x*w0[12] + a3.y*w0[13] + a3.z*w0[14] + a3.w*w0[15];
    emb1 += a3.x*w1[12] + a3.y*w1[13] + a3.z*w1[14] + a3.w*w1[15];
    __half2 qh = *(const __half2*)(qb + (size_t)src * Hh + c0);
    __half2 vh = *(const __half2*)(vb + (size_t)src * Hh + c0);
    float g0 = k0 + emb0 + __half2float(qh.x);
    float g1 = k1 + emb1 + __half2float(qh.y);
    g0 = 1.f / (1.f + __expf(-g0));
    g1 = 1.f / (1.f + __expf(-g1));
    agg0 += g0 * __half2float(vh.x);
    agg1 += g1 * __half2float(vh.y);
  }

  // skip + LayerNorm + GELU (wave owns full row: 2 channels/lane)
  float2 hv = *(float2*)(hbuf + (size_t)row * Hh + c0);
  float y0 = hv.x + agg0, y1 = hv.y + agg1;
  float s = y0 + y1;
#pragma unroll
  for (int off = 32; off; off >>= 1) s += __shfl_xor(s, off);
  float mu = s * (1.f / 128.f);
  float d0 = y0 - mu, d1 = y1 - mu;
  float vv = d0 * d0 + d1 * d1;
#pragma unroll
  for (int off = 32; off; off >>= 1) vv += __shfl_xor(vv, off);
  float rstd = rsqrtf(vv * (1.f / 128.f) + 1e-5f);
  float2 lg = *(const float2*)(ln_g_l + c0);
  float2 lb = *(const float2*)(ln_b_l + c0);
  float o0 = d0 * rstd * lg.x + lb.x;
  float o1 = d1 * rstd * lg.y + lb.y;
  o0 = 0.5f * o0 * (1.f + erff(o0 * 0.70710678118654752f));
  o1 = 0.5f * o1 * (1.f + erff(o1 * 0.70710678118654752f));
  *(float2*)(hbuf + (size_t)row * Hh + c0) = make_float2(o0, o1);
}

// ---- out_proj: out = h @ out_w  [N,128]@[128,64] ----
__global__ __launch_bounds__(64) void out_proj_kernel(const float* __restrict__ h,
    const float* __restrict__ w, float* __restrict__ out) {
  __shared__ float hs[16][Hh];
  int r0 = blockIdx.x * 16;
  for (int i = threadIdx.x; i < 16 * Hh; i += 64) {
    int r = i >> 7, c = i & 127;
    int rr = r0 + r;
    hs[r][c] = (rr < Nn) ? h[rr * Hh + c] : 0.f;
  }
  __syncthreads();
  int t = threadIdx.x;
  float acc[16] = {};
  for (int kk = 0; kk < Hh; kk++) {
    float wv = w[kk * NOUT + t];
#pragma unroll
    for (int r = 0; r < 16; r++) acc[r] += hs[r][kk] * wv;
  }
#pragma unroll
  for (int r = 0; r < 16; r++) {
    int rr = r0 + r;
    if (rr < Nn) out[rr * NOUT + t] = acc[r];
  }
}

extern "C" void kernel_launch(void* const* d_in, const int* in_sizes, int n_in,
                              void* d_out, int out_size, void* d_ws, size_t ws_size,
                              hipStream_t stream) {
  const float* x    = (const float*)d_in[0];
  const int*   ei   = (const int*)d_in[1];
  const float* ea   = (const float*)d_in[2];
  const float* in_w = (const float*)d_in[3];
  const float* in_b = (const float*)d_in[4];
  const float* Wk   = (const float*)d_in[5];
  const float* bk   = (const float*)d_in[6];
  const float* Wq   = (const float*)d_in[7];
  const float* bq   = (const float*)d_in[8];
  const float* Wv   = (const float*)d_in[9];
  const float* bv   = (const float*)d_in[10];
  const float* We   = (const float*)d_in[11];
  const float* be   = (const float*)d_in[12];
  const float* Ws   = (const float*)d_in[13];
  const float* bs   = (const float*)d_in[14];
  const float* ln_g = (const float*)d_in[15];
  const float* ln_b = (const float*)d_in[16];
  const float* out_w = (const float*)d_in[17];
  float* out = (float*)d_out;

  const int* ei_src = ei;
  const int* ei_dst = ei + Ee;

  size_t NH = (size_t)Nn * Hh;
  char* wsp = (char*)d_ws;
  float*  hA = (float*)wsp;           wsp += NH * 4;
  float*  hB = (float*)wsp;           wsp += NH * 4;
  __half* kb = (__half*)wsp;          wsp += NH * 2;
  __half* qb = (__half*)wsp;          wsp += NH * 2;
  __half* vb = (__half*)wsp;          wsp += NH * 2;
  int* rowptr = (int*)wsp;            wsp += (Nn + 1) * 4;
  int* cursor = (int*)wsp;            wsp += Nn * 4;
  int* bsums  = (int*)wsp;            wsp += 128 * 4;
  int* eid    = (int*)wsp;            wsp += (size_t)Ee * 4;

  const int NB_SCAN = (Nn + 1023) / 1024;   // 98

  // CSR build (edge_index shared by all layers)
  zero_kernel<<<(Nn + 255) / 256, 256, 0, stream>>>(cursor, Nn);
  hist_kernel<<<(Ee + 255) / 256, 256, 0, stream>>>(ei_dst, cursor);
  scan_block_kernel<<<NB_SCAN, 256, 0, stream>>>(cursor, rowptr, bsums);
  scan_sums_kernel<<<1, 128, 0, stream>>>(bsums, NB_SCAN);
  finalize_rowptr_kernel<<<(Nn + 1 + 255) / 256, 256, 0, stream>>>(rowptr, bsums, cursor);
  fill_kernel<<<(Ee + 255) / 256, 256, 0, stream>>>(ei_dst, cursor, eid);

  in_proj_kernel<<<(Nn + 7) / 8, 128, 0, stream>>>(x, in_w, in_b, hA);

  float* h  = hA;
  float* hn = hB;
  for (int l = 0; l < NL; l++) {
    kqvs_kernel<<<(Nn + 7) / 8, 128, 0, stream>>>(h,
        Wk + l * Hh * Hh, bk + l * Hh,
        Wq + l * Hh * Hh, bq + l * Hh,
        Wv + l * Hh * Hh, bv + l * Hh,
        Ws + l * Hh * Hh, bs + l * Hh,
        kb, qb, vb, hn);
    edge_csr_kernel<<<Nn / 4, 256, 0, stream>>>(kb, qb, vb, ei_src, ea,
        rowptr, eid, We + l * EDIMM * Hh, be + l * Hh,
        ln_g + l * Hh, ln_b + l * Hh, hn);
    float* tmp = h; h = hn; hn = tmp;
  }

  out_proj_kernel<<<(Nn + 15) / 16, 64, 0, stream>>>(h, out_w, out);
}